// Round 2
// baseline (240.876 us; speedup 1.0000x reference)
//
#include <hip/hip_runtime.h>

// PSU LIF: V_t = b*V_{t-1} + x_t ; R_t = b*R_{t-1} + sigmoid(V_t)
// out0 = (V - R - 1 > 0), out1 = V.  x:[16,1024,1024] f32, beta:[1024] f32.
//
// Round-2 structure: chunked scan with in-block carry propagation.
//   block = 1024 threads = 64 sequences (consecutive h) x 16 chunks (L=64).
//   wave  = one chunk index over 64 consecutive h -> coalesced 256B accesses.
//   Each thread: chunk in registers (f32 arr[64], f64 running scans);
//   carries exchanged through LDS (A = b^L, B = local chunk sum), 15 f64 fmas.
//   4096 waves = 4 waves/SIMD (vs 0.25 in round 1) to hide HBM latency.
// Traffic optimum: read x 67MB, write V+spike 134MB.

#define BB 16
#define TT 1024
#define HH 1024
#define L 64            // chunk length (timesteps per thread)
#define C 16            // chunks per sequence = TT/L
#define SEQ 64          // sequences per block

__global__ __launch_bounds__(1024, 4) void lif_scan(const float* __restrict__ x,
                                                    const float* __restrict__ beta,
                                                    float* __restrict__ out_spike,
                                                    float* __restrict__ out_v) {
    __shared__ double lds_sum[C][SEQ];      // 8 KB: chunk-final scan values

    const int tid = threadIdx.x;
    const int c = tid >> 6;                 // chunk index = wave index (uniform per wave)
    const int s = tid & 63;                 // sequence-in-block = lane
    const int blk = blockIdx.x;             // 256 blocks
    const int b = blk >> 4;                 // batch (16 blocks per batch)
    const int h = ((blk & 15) << 6) + s;    // hidden index

    const float bf = fminf(fmaxf(beta[h], 0.0f), 1.0f);
    const double bd = (double)bf;
    double pwL = bd;                        // b^L via 6 squarings (L=64)
#pragma unroll
    for (int k = 0; k < 6; ++k) pwL *= pwL;

    const size_t base = (size_t)b * TT * HH + (size_t)(c * L) * HH + (size_t)h;
    const float* __restrict__ xp = x + base;
    float* __restrict__ vp = out_v + base;
    float* __restrict__ sp = out_spike + base;

    // ---- load chunk ----
    float arr[L];
#pragma unroll
    for (int i = 0; i < L; ++i) arr[i] = xp[(size_t)i * HH];

    // ---- phase A: local V scan (zero init), keep local values f32 ----
    double Vd = 0.0;
#pragma unroll
    for (int i = 0; i < L; ++i) {
        Vd = fma(bd, Vd, (double)arr[i]);
        arr[i] = (float)Vd;
    }
    lds_sum[c][s] = Vd;
    __syncthreads();

    // ---- V carry: V_start(c) = sum_{j<c} (b^L)^(c-1-j) * Bsum_j ----
    double Vstart = 0.0;
    for (int j = 0; j < c; ++j) Vstart = fma(pwL, Vstart, lds_sum[j][s]);
    __syncthreads();                        // all reads done before R-phase writes

    // ---- phase B: exact V, write V, sigmoid, local R scan ----
    double vcarry = Vstart;
    double Rd = 0.0;
#pragma unroll
    for (int i = 0; i < L; ++i) {
        vcarry *= bd;                       // b^(i+1) * Vstart
        const float vfull = arr[i] + (float)vcarry;
        vp[(size_t)i * HH] = vfull;
        const float sg = 1.0f / (1.0f + __expf(-vfull));
        Rd = fma(bd, Rd, (double)sg);
        arr[i] = vfull - (float)Rd;         // e_i = V_i - localR_i
    }
    lds_sum[c][s] = Rd;
    __syncthreads();

    // ---- R carry ----
    double Rstart = 0.0;
    for (int j = 0; j < c; ++j) Rstart = fma(pwL, Rstart, lds_sum[j][s]);

    // ---- phase C: spike = (V - R - 1 > 0) = (e_i - b^(i+1)*Rstart > 1) ----
    double rcarry = Rstart;
#pragma unroll
    for (int i = 0; i < L; ++i) {
        rcarry *= bd;
        sp[(size_t)i * HH] = (arr[i] - (float)rcarry > 1.0f) ? 1.0f : 0.0f;
    }
}

extern "C" void kernel_launch(void* const* d_in, const int* in_sizes, int n_in,
                              void* d_out, int out_size, void* d_ws, size_t ws_size,
                              hipStream_t stream) {
    const float* x = (const float*)d_in[0];
    const float* beta = (const float*)d_in[1];
    float* out = (float*)d_out;
    float* out_spike = out;                              // [16,1024,1024]
    float* out_v = out + (size_t)BB * TT * HH;           // [16,1024,1024]

    const int grid = (BB * HH) / SEQ;                    // 256 blocks
    lif_scan<<<grid, 1024, 0, stream>>>(x, beta, out_spike, out_v);
}

// Round 3
// 190.070 us; speedup vs baseline: 1.2673x; 1.2673x over previous
//
#include <hip/hip_runtime.h>

// PSU LIF: V_t = b*V_{t-1} + x_t ; R_t = b*R_{t-1} + sigmoid(V_t)
// out0 = (V - R - 1 > 0), out1 = V.  x:[16,1024,1024] f32, beta:[1024] f32.
//
// Round-3: chunked in-block scan, f32 only, chunk shrunk to avoid spill.
//   block = 1024 thr = 32 sequences (consecutive h) x 32 chunks (L=32).
//   Round 2 lesson: arr[64]+f64 spilled (VGPR capped 64, +165MB scratch HBM
//   traffic). arr[32] f32 (~56 VGPR) stays in registers.
//   Wave = 2 chunks x 32 seqs -> 2x128B segments per access, coalesced.
//   Carries across chunks via two 4KB LDS buffers, serial fma (<=31 iters).
// Traffic optimum: read x 67MB, write V+spike 134MB.

#define BB 16
#define TT 1024
#define HH 1024
#define L 32            // timesteps per thread
#define C 32            // chunks per sequence = TT/L
#define SEQ 32          // sequences per block

__global__ __launch_bounds__(1024, 4) void lif_scan(const float* __restrict__ x,
                                                    const float* __restrict__ beta,
                                                    float* __restrict__ out_spike,
                                                    float* __restrict__ out_v) {
    __shared__ float lds_v[C][SEQ];         // 4 KB: chunk-final local V sums
    __shared__ float lds_r[C][SEQ];         // 4 KB: chunk-final local R sums

    const int tid = threadIdx.x;
    const int c = tid >> 5;                 // chunk index 0..31
    const int s = tid & 31;                 // sequence-in-block 0..31
    const int blk = blockIdx.x;             // 512 blocks
    const int b = blk >> 5;                 // batch (32 blocks per batch)
    const int h = ((blk & 31) << 5) + s;    // hidden index

    const float bf = fminf(fmaxf(beta[h], 0.0f), 1.0f);
    float pwL = bf;                         // b^L via 5 squarings (L=32)
#pragma unroll
    for (int k = 0; k < 5; ++k) pwL *= pwL;

    const size_t base = (size_t)b * TT * HH + (size_t)(c * L) * HH + (size_t)h;
    const float* __restrict__ xp = x + base;
    float* __restrict__ vp = out_v + base;
    float* __restrict__ sp = out_spike + base;

    // ---- load chunk (32 independent loads in flight) ----
    float arr[L];
#pragma unroll
    for (int i = 0; i < L; ++i) arr[i] = xp[(size_t)i * HH];

    // ---- phase A: local V scan (zero init) ----
    float V = 0.0f;
#pragma unroll
    for (int i = 0; i < L; ++i) {
        V = fmaf(bf, V, arr[i]);
        arr[i] = V;
    }
    lds_v[c][s] = V;
    __syncthreads();

    // ---- V carry: Vstart(c) = sum_{j<c} (b^L)^(c-1-j) * vsum_j ----
    float Vstart = 0.0f;
    for (int j = 0; j < c; ++j) Vstart = fmaf(pwL, Vstart, lds_v[j][s]);

    // ---- phase B: exact V, write V, sigmoid, local R scan ----
    float vcarry = Vstart;
    float R = 0.0f;
#pragma unroll
    for (int i = 0; i < L; ++i) {
        vcarry *= bf;                       // b^(i+1) * Vstart
        const float vfull = arr[i] + vcarry;
        vp[(size_t)i * HH] = vfull;
        const float sg = 1.0f / (1.0f + __expf(-vfull));
        R = fmaf(bf, R, sg);
        arr[i] = vfull - R;                 // e_i = V_i - localR_i
    }
    lds_r[c][s] = R;
    __syncthreads();

    // ---- R carry ----
    float Rstart = 0.0f;
    for (int j = 0; j < c; ++j) Rstart = fmaf(pwL, Rstart, lds_r[j][s]);

    // ---- phase C: spike = (e_i - b^(i+1)*Rstart > 1) ----
    float rcarry = Rstart;
#pragma unroll
    for (int i = 0; i < L; ++i) {
        rcarry *= bf;
        sp[(size_t)i * HH] = (arr[i] - rcarry > 1.0f) ? 1.0f : 0.0f;
    }
}

extern "C" void kernel_launch(void* const* d_in, const int* in_sizes, int n_in,
                              void* d_out, int out_size, void* d_ws, size_t ws_size,
                              hipStream_t stream) {
    const float* x = (const float*)d_in[0];
    const float* beta = (const float*)d_in[1];
    float* out = (float*)d_out;
    float* out_spike = out;                              // [16,1024,1024]
    float* out_v = out + (size_t)BB * TT * HH;           // [16,1024,1024]

    const int grid = (BB * HH) / SEQ;                    // 512 blocks
    lif_scan<<<grid, 1024, 0, stream>>>(x, beta, out_spike, out_v);
}